// Round 11
// baseline (4534.828 us; speedup 1.0000x reference)
//
#include <hip/hip_runtime.h>
#include <cstdint>
#include <cstddef>

typedef unsigned long long ull;
typedef unsigned int uint32;

// B=16, T=128, K=1024, D=768, KP=102
// Persistent scan, batch-quad (p=4) on the R8/R9 flag protocol:
//  G=4 groups x S=64 slices x 16 cols. fwd bids 0..255 (g*64+s, expT bf16),
//  vit bids 256..511 (g*64+s, tr fp32 exact). Grid 512 = exactly 2 blocks/CU.
//  Approx folded into fwd s<4 blocks; backtrace into vit s<4 blocks.
// Conflict-free LDS state reads: wave=row-band, lane=(bq,cg,rh), rotation
// (ii + 2*(4bq+rh))&63 puts the 16 distinct addresses on 16 distinct banks.
// All cross-block stores by wave 0 via sc0sc1 bypass; flag = wave0 vmcnt
// drain + plain bypass store to a private 64B line; consumers poll read-only.

// ---- workspace layout (float offsets) ----
#define OFF_EM    ((size_t)0)         // emission   2048*1024 f32
#define OFF_TR    ((size_t)2097152)   // transition 1024*1024 f32
#define OFF_EXPTB ((size_t)3145728)   // expTb      1024*1024 bf16 (ushort)
#define OFF_UPP   ((size_t)3670016)   // u ping-pong 2*16*1024
#define OFF_APP   ((size_t)3702784)   // av ping-pong 2*16*1024
#define OFF_ULST  ((size_t)3735552)   // u at t=tb   16*1024
#define OFF_ALST  ((size_t)3751936)   // av at t=tb  16*1024
#define OFF_UALST ((size_t)3768320)   // ua at t=tb  16*102
#define OFF_ETOP  ((size_t)3769952)   // em_top      2048*102
#define OFF_ITOP  ((size_t)3978848)   // top_idx     2048*102 (int)
#define OFF_RMAX  ((size_t)4187744)   // row_max     2048
#define OFF_RLSE  ((size_t)4189792)   // row_lse     2048
#define OFF_SMP   ((size_t)4191840)   // sm_pred     2048 (int)
#define OFF_BP    ((size_t)4193888)   // bp          128*16*1024 (int)
#define OFF_FLG   ((size_t)6291040)   // flags 8grp x 128t x 64s x 16u = 4MB

#define FLAG_PAD 16  // uints per flag = 64B line each

__device__ __forceinline__ unsigned short f2bf(float f) {
  uint32 u = __builtin_bit_cast(uint32, f);
  u = (u + 0x7fffu + ((u >> 16) & 1u)) >> 16;
  return (unsigned short)u;
}
__device__ __forceinline__ float bflo(uint32 w) {
  return __builtin_bit_cast(float, w << 16);
}
__device__ __forceinline__ float bfhi(uint32 w) {
  return __builtin_bit_cast(float, w & 0xffff0000u);
}

// ---------------- GEMM: [x_emb; state] (3072x768) @ state^T -> 3072x1024 ----
__global__ __launch_bounds__(256) void gemm_kernel(
    const float* __restrict__ x, const float* __restrict__ stm,
    float* __restrict__ emission, float* __restrict__ transition,
    unsigned short* __restrict__ expTb) {
  __shared__ float As[16][68];
  __shared__ float Bs[16][68];
  const int tid = threadIdx.x;
  const int tx = tid & 15, ty = tid >> 4;
  const int m0 = blockIdx.x * 64, n0 = blockIdx.y * 64;
  const int lr = tid >> 2;
  const int lc = (tid & 3) << 2;
  float acc[4][4] = {};
  const float* aptr;
  {
    int gr = m0 + lr;
    aptr = (gr < 2048) ? (x + (size_t)gr * 768) : (stm + (size_t)(gr - 2048) * 768);
  }
  const float* bptr = stm + (size_t)(n0 + lr) * 768;
  for (int k0 = 0; k0 < 768; k0 += 16) {
    float4 a4 = *(const float4*)(aptr + k0 + lc);
    float4 b4 = *(const float4*)(bptr + k0 + lc);
    __syncthreads();
    As[lc + 0][lr] = a4.x; As[lc + 1][lr] = a4.y; As[lc + 2][lr] = a4.z; As[lc + 3][lr] = a4.w;
    Bs[lc + 0][lr] = b4.x; Bs[lc + 1][lr] = b4.y; Bs[lc + 2][lr] = b4.z; Bs[lc + 3][lr] = b4.w;
    __syncthreads();
#pragma unroll
    for (int kk = 0; kk < 16; ++kk) {
      float a[4], b[4];
#pragma unroll
      for (int q = 0; q < 4; ++q) a[q] = As[kk][ty * 4 + q];
#pragma unroll
      for (int q = 0; q < 4; ++q) b[q] = Bs[kk][tx * 4 + q];
#pragma unroll
      for (int i2 = 0; i2 < 4; ++i2)
#pragma unroll
        for (int j2 = 0; j2 < 4; ++j2) acc[i2][j2] += a[i2] * b[j2];
    }
  }
  const float rs = 0.03608439182435161f;  // 1/sqrt(768)
#pragma unroll
  for (int i2 = 0; i2 < 4; ++i2) {
    int r = m0 + ty * 4 + i2;
#pragma unroll
    for (int j2 = 0; j2 < 4; ++j2) {
      int c = n0 + tx * 4 + j2;
      float v = acc[i2][j2] * rs;
      if (r < 2048) {
        emission[(size_t)r * 1024 + c] = v;
      } else {
        size_t o = (size_t)(r - 2048) * 1024 + c;
        transition[o] = v;
        expTb[o] = f2bf(expf(v));
      }
    }
  }
}

// ---------------- per-row bitonic sort -> top-102 set, max, lse, argmax ----
__global__ __launch_bounds__(256) void topk_kernel(
    const float* __restrict__ emission, float* __restrict__ em_top,
    int* __restrict__ top_idx, float* __restrict__ row_max,
    float* __restrict__ row_lse, int* __restrict__ sm_pred) {
  __shared__ float v[1024];
  __shared__ int ix[1024];
  __shared__ float rb[256];
  const int row = blockIdx.x;
  const int tid = threadIdx.x;
  const float* e = emission + (size_t)row * 1024;
  for (int p = tid; p < 1024; p += 256) { v[p] = e[p]; ix[p] = p; }
  __syncthreads();
  for (int k = 2; k <= 1024; k <<= 1) {
    for (int j = k >> 1; j > 0; j >>= 1) {
      for (int p = tid; p < 1024; p += 256) {
        int l = p ^ j;
        if (l > p) {
          float va = v[p], vb = v[l];
          int ia = ix[p], ib = ix[l];
          bool aBefore = (va > vb) || (va == vb && ia < ib);
          bool up = ((p & k) == 0);
          if (up ? !aBefore : aBefore) { v[p] = vb; v[l] = va; ix[p] = ib; ix[l] = ia; }
        }
      }
      __syncthreads();
    }
  }
  float mx = v[0];
  float s = 0.f;
  for (int p = tid; p < 1024; p += 256) s += expf(v[p] - mx);
  rb[tid] = s; __syncthreads();
  for (int w = 128; w > 0; w >>= 1) { if (tid < w) rb[tid] += rb[tid + w]; __syncthreads(); }
  if (tid == 0) {
    row_max[row] = mx;
    row_lse[row] = mx + logf(rb[0]);
    sm_pred[row] = ix[0];
  }
  for (int p = tid; p < 102; p += 256) {
    em_top[(size_t)row * 102 + p] = v[p];
    top_idx[(size_t)row * 102 + p] = ix[p];
  }
}

// ---------------- coherence helpers ----
__device__ __forceinline__ void store_bypass_f(float* p, float v) {
  __hip_atomic_store(p, v, __ATOMIC_RELAXED, __HIP_MEMORY_SCOPE_AGENT);
}
__device__ __forceinline__ void store_bypass2(float* p, float2 v) {
  __hip_atomic_store((ull*)p, __builtin_bit_cast(ull, v),
                     __ATOMIC_RELAXED, __HIP_MEMORY_SCOPE_AGENT);
}
__device__ __forceinline__ void store_bypass_i2(int* p, int2 v) {
  __hip_atomic_store((ull*)p, __builtin_bit_cast(ull, v),
                     __ATOMIC_RELAXED, __HIP_MEMORY_SCOPE_AGENT);
}
__device__ __forceinline__ float load_bypass_f(const float* p) {
  return __hip_atomic_load(p, __ATOMIC_RELAXED, __HIP_MEMORY_SCOPE_AGENT);
}
__device__ __forceinline__ int load_bypass_i(const int* p) {
  return __hip_atomic_load(p, __ATOMIC_RELAXED, __HIP_MEMORY_SCOPE_AGENT);
}

__device__ __forceinline__ void flag_set(unsigned* f) {
  asm volatile("s_waitcnt vmcnt(0)" ::: "memory");
  __hip_atomic_store(f, 1u, __ATOMIC_RELAXED, __HIP_MEMORY_SCOPE_AGENT);
}
__device__ __forceinline__ void flag_poll(const unsigned* f) {
  while (__hip_atomic_load(f, __ATOMIC_RELAXED, __HIP_MEMORY_SCOPE_AGENT) == 0u)
    __builtin_amdgcn_s_sleep(1);
}

// stage 4 batches' state (4096 floats = 2048 ull) into LDS
__device__ __forceinline__ void stage_quad(const float* __restrict__ src,
                                           float* __restrict__ st, int tid) {
  const ull* s8 = (const ull*)src;
  ull* l8 = (ull*)st;
#pragma unroll
  for (int m = 0; m < 8; ++m)
    l8[tid + m * 256] =
        __hip_atomic_load(s8 + tid + m * 256, __ATOMIC_RELAXED, __HIP_MEMORY_SCOPE_AGENT);
}

// flag address: ((grp*128 + t)*64 + slice) * FLAG_PAD
__device__ __forceinline__ unsigned* flag_at(unsigned* base, int grp, int t, int s) {
  return base + ((size_t)(grp * 128 + t) * 64 + s) * FLAG_PAD;
}

// ---------------- persistent scan ----
__global__ __launch_bounds__(256, 2) void scan_kernel(
    const float* __restrict__ em, const float* __restrict__ tr,
    const unsigned short* __restrict__ expTb, const float* __restrict__ em_top,
    const int* __restrict__ top_idx, const int* __restrict__ y_lens,
    float* __restrict__ u_pp, float* __restrict__ av_pp,
    float* __restrict__ u_last, float* __restrict__ av_last,
    float* __restrict__ ua_last, int* __restrict__ bp,
    unsigned* __restrict__ flags, float* __restrict__ out_crf) {
  __shared__ __align__(16) float st[4096];   // 4 batches x 1024 state
  __shared__ __align__(16) float psv[192];   // 3-band partials (64 results)
  __shared__ __align__(16) int psi[192];
  __shared__ float sua[2][102];
  __shared__ int sidxp[102], sidxc[102];
  __shared__ float aps[102];
  __shared__ float swv[4];
  __shared__ int swi[4];
  const int bid = blockIdx.x, tid = threadIdx.x;
  const int w = tid >> 6, l = tid & 63;
  const int bq = l >> 4, cg = (l >> 2) & 3, rh = l & 3;
  const int rb0 = w * 256 + rh * 64;
  const int rot = 2 * (bq * 4 + rh);   // 16 distinct banks for (bq,rh)

  if (bid < 256) {
    // ======== forward: group g (4 batches), slice s (16 cols, bf16 expT) ====
    const int g = bid >> 6, s = bid & 63;
    const int grp = g;
    const int b = g * 4 + bq;
    const int tbq = y_lens[b] - 1;
    const int j0 = s * 16 + cg * 4;
    const bool doApprox = (s < 4);
    const int ab = g * 4 + s;            // approx batch if doApprox
    int atb = 0;
    if (doApprox) atb = y_lens[ab] - 1;
    // t=0 init (wave 0 only: 4 bq x 16 cols)
    if (tid < 64) {
      const int bb = g * 4 + (tid >> 4);
      const int c = s * 16 + (tid & 15);
      float v = expf(em[(size_t)(bb * 128) * 1024 + c]);
      store_bypass_f(u_pp + bb * 1024 + c, v);
      if (y_lens[bb] == 1) u_last[bb * 1024 + c] = v;
    }
    if (doApprox && tid < 102) {
      float v = expf(em_top[(size_t)(ab * 128) * 102 + tid]);
      sua[0][tid] = v;
      if (atb == 0) ua_last[ab * 102 + tid] = v;
    }
    if (tid == 0) flag_set(flag_at(flags, grp, 0, s));
    for (int t = 1; t < 128; ++t) {
      if (tid < 64) flag_poll(flag_at(flags, grp, t - 1, tid));
      __syncthreads();
      stage_quad(u_pp + ((t - 1) & 1) * 16384 + g * 4096, st, tid);
      __syncthreads();
      const float* stb = st + bq * 1024;
      float a0 = 0.f, a1 = 0.f, a2 = 0.f, a3 = 0.f;
#pragma unroll 8
      for (int ii = 0; ii < 64; ++ii) {
        const int row = rb0 + ((ii + rot) & 63);
        const uint2 wv = *(const uint2*)(expTb + (size_t)row * 1024 + j0);
        const float ui = stb[row];
        a0 += ui * bflo(wv.x); a1 += ui * bfhi(wv.x);
        a2 += ui * bflo(wv.y); a3 += ui * bfhi(wv.y);
      }
      // merge across rh (lane bits 0,1)
#pragma unroll
      for (int off = 1; off <= 2; off <<= 1) {
        a0 += __shfl_xor(a0, off); a1 += __shfl_xor(a1, off);
        a2 += __shfl_xor(a2, off); a3 += __shfl_xor(a3, off);
      }
      if (w > 0 && rh == 0) {
        float* p = psv + (w - 1) * 64 + bq * 16 + cg * 4;
        p[0] = a0; p[1] = a1; p[2] = a2; p[3] = a3;
      }
      __syncthreads();
      if (w == 0 && rh == 0) {
#pragma unroll
        for (int q2 = 0; q2 < 3; ++q2) {
          const float* p = psv + q2 * 64 + bq * 16 + cg * 4;
          a0 += p[0]; a1 += p[1]; a2 += p[2]; a3 += p[3];
        }
        const float4 e4 = *(const float4*)(em + ((size_t)b * 128 + t) * 1024 + j0);
        float v0 = a0 * expf(e4.x) * (1.0f / 1024.0f);
        float v1 = a1 * expf(e4.y) * (1.0f / 1024.0f);
        float v2 = a2 * expf(e4.z) * (1.0f / 1024.0f);
        float v3 = a3 * expf(e4.w) * (1.0f / 1024.0f);
        float* dst = u_pp + (t & 1) * 16384 + b * 1024 + j0;
        store_bypass2(dst, make_float2(v0, v1));
        store_bypass2(dst + 2, make_float2(v2, v3));
        if (t == tbq) {
          float* ul = u_last + b * 1024 + j0;
          ul[0] = v0; ul[1] = v1; ul[2] = v2; ul[3] = v3;
        }
      }
      if (doApprox) {
        if (tid < 102) {
          sidxp[tid] = top_idx[((size_t)ab * 128 + (t - 1)) * 102 + tid];
          sidxc[tid] = top_idx[((size_t)ab * 128 + t) * 102 + tid];
        }
        __syncthreads();
        const int j2 = tid & 127, h2 = tid >> 7;
        float acc2 = 0.f;
        if (j2 < 102) {
          const int col = sidxc[j2];
          const float* up = sua[(t - 1) & 1];
          for (int i = h2 * 51; i < h2 * 51 + 51; ++i)
            acc2 += up[i] * bflo((uint32)expTb[(size_t)sidxp[i] * 1024 + col]);
        }
        if (h2 == 1 && j2 < 102) aps[j2] = acc2;
        __syncthreads();
        if (h2 == 0 && j2 < 102) {
          acc2 += aps[j2];
          float e = em_top[((size_t)ab * 128 + t) * 102 + j2];
          float nv = acc2 * expf(e) * (1.0f / 102.0f);
          sua[t & 1][j2] = nv;
          if (t == atb) ua_last[ab * 102 + j2] = nv;
        }
      }
      if (tid == 0) flag_set(flag_at(flags, grp, t, s));
    }
  } else {
    // ======== viterbi: group g, slice s (16 cols, fp32 tr, exact) ========
    const int local = bid - 256;
    const int g = local >> 6, s = local & 63;
    const int grp = 4 + g;
    const int b = g * 4 + bq;
    const int tbq = y_lens[b] - 1;
    const int j0 = s * 16 + cg * 4;
    // t=0 init (wave 0 only)
    if (tid < 64) {
      const int bb = g * 4 + (tid >> 4);
      const int c = s * 16 + (tid & 15);
      float v = em[(size_t)(bb * 128) * 1024 + c];
      store_bypass_f(av_pp + bb * 1024 + c, v);
      if (y_lens[bb] == 1) store_bypass_f(av_last + bb * 1024 + c, v);
    }
    if (tid == 0) flag_set(flag_at(flags, grp, 0, s));
    for (int t = 1; t < 128; ++t) {
      if (tid < 64) flag_poll(flag_at(flags, grp, t - 1, tid));
      __syncthreads();
      stage_quad(av_pp + ((t - 1) & 1) * 16384 + g * 4096, st, tid);
      __syncthreads();
      const float* ab2 = st + bq * 1024;
      float mv0 = -3.0e38f, mv1 = -3.0e38f, mv2 = -3.0e38f, mv3 = -3.0e38f;
      int mi0 = 0x7fffffff, mi1 = 0x7fffffff, mi2 = 0x7fffffff, mi3 = 0x7fffffff;
#pragma unroll 8
      for (int ii = 0; ii < 64; ++ii) {
        const int row = rb0 + ((ii + rot) & 63);
        const float4 t4 = *(const float4*)(tr + (size_t)row * 1024 + j0);
        const float ai = ab2[row];
        float c0 = ai + t4.x, c1 = ai + t4.y, c2 = ai + t4.z, c3 = ai + t4.w;
        if (c0 > mv0 || (c0 == mv0 && row < mi0)) { mv0 = c0; mi0 = row; }
        if (c1 > mv1 || (c1 == mv1 && row < mi1)) { mv1 = c1; mi1 = row; }
        if (c2 > mv2 || (c2 == mv2 && row < mi2)) { mv2 = c2; mi2 = row; }
        if (c3 > mv3 || (c3 == mv3 && row < mi3)) { mv3 = c3; mi3 = row; }
      }
      // merge across rh (lane bits 0,1), index tie-break
#pragma unroll
      for (int off = 1; off <= 2; off <<= 1) {
        float ov; int oi;
        ov = __shfl_xor(mv0, off); oi = __shfl_xor(mi0, off);
        if (ov > mv0 || (ov == mv0 && oi < mi0)) { mv0 = ov; mi0 = oi; }
        ov = __shfl_xor(mv1, off); oi = __shfl_xor(mi1, off);
        if (ov > mv1 || (ov == mv1 && oi < mi1)) { mv1 = ov; mi1 = oi; }
        ov = __shfl_xor(mv2, off); oi = __shfl_xor(mi2, off);
        if (ov > mv2 || (ov == mv2 && oi < mi2)) { mv2 = ov; mi2 = oi; }
        ov = __shfl_xor(mv3, off); oi = __shfl_xor(mi3, off);
        if (ov > mv3 || (ov == mv3 && oi < mi3)) { mv3 = ov; mi3 = oi; }
      }
      if (w > 0 && rh == 0) {
        const int o = (w - 1) * 64 + bq * 16 + cg * 4;
        psv[o] = mv0; psv[o + 1] = mv1; psv[o + 2] = mv2; psv[o + 3] = mv3;
        psi[o] = mi0; psi[o + 1] = mi1; psi[o + 2] = mi2; psi[o + 3] = mi3;
      }
      __syncthreads();
      if (w == 0 && rh == 0) {
#pragma unroll
        for (int q2 = 0; q2 < 3; ++q2) {
          const int o = q2 * 64 + bq * 16 + cg * 4;
          float pv; int pi;
          pv = psv[o]; pi = psi[o];
          if (pv > mv0 || (pv == mv0 && pi < mi0)) { mv0 = pv; mi0 = pi; }
          pv = psv[o + 1]; pi = psi[o + 1];
          if (pv > mv1 || (pv == mv1 && pi < mi1)) { mv1 = pv; mi1 = pi; }
          pv = psv[o + 2]; pi = psi[o + 2];
          if (pv > mv2 || (pv == mv2 && pi < mi2)) { mv2 = pv; mi2 = pi; }
          pv = psv[o + 3]; pi = psi[o + 3];
          if (pv > mv3 || (pv == mv3 && pi < mi3)) { mv3 = pv; mi3 = pi; }
        }
        const float4 e4 = *(const float4*)(em + ((size_t)b * 128 + t) * 1024 + j0);
        float nv0 = mv0 + e4.x, nv1 = mv1 + e4.y;
        float nv2 = mv2 + e4.z, nv3 = mv3 + e4.w;
        float* dst = av_pp + (t & 1) * 16384 + b * 1024 + j0;
        store_bypass2(dst, make_float2(nv0, nv1));
        store_bypass2(dst + 2, make_float2(nv2, nv3));
        int* bpd = bp + (size_t)t * 16384 + b * 1024 + j0;
        store_bypass_i2(bpd, make_int2(mi0, mi1));
        store_bypass_i2(bpd + 2, make_int2(mi2, mi3));
        if (t == tbq) {
          float* al = av_last + b * 1024 + j0;
          store_bypass2(al, make_float2(nv0, nv1));
          store_bypass2(al + 2, make_float2(nv2, nv3));
        }
      }
      if (tid == 0) flag_set(flag_at(flags, grp, t, s));
    }
    // ---- backtrace: vit blocks s<4 handle batch g*4+s ----
    if (s < 4) {
      if (tid < 64) flag_poll(flag_at(flags, grp, 127, tid));
      __syncthreads();
      const int bb = g * 4 + s;
      const int tbb = y_lens[bb] - 1;
      for (int t2 = tbb + 1 + tid; t2 < 128; t2 += 256) out_crf[bb * 128 + t2] = 0.f;
      const float* al = av_last + bb * 1024;
      float bv = -3.0e38f;
      int bi = 0x7fffffff;
      for (int i = tid; i < 1024; i += 256) {
        float val = load_bypass_f(al + i);
        if (val > bv || (val == bv && i < bi)) { bv = val; bi = i; }
      }
      for (int off = 32; off > 0; off >>= 1) {
        float ov = __shfl_xor(bv, off);
        int oi = __shfl_xor(bi, off);
        if (ov > bv || (ov == bv && oi < bi)) { bv = ov; bi = oi; }
      }
      if ((tid & 63) == 0) { swv[tid >> 6] = bv; swi[tid >> 6] = bi; }
      __syncthreads();
      if (tid == 0) {
        for (int q = 1; q < 4; ++q)
          if (swv[q] > bv || (swv[q] == bv && swi[q] < bi)) { bv = swv[q]; bi = swi[q]; }
        int sx = bi;
        out_crf[bb * 128 + tbb] = (float)sx;
        for (int t2 = tbb - 1; t2 >= 0; --t2) {
          sx = load_bypass_i(bp + (size_t)(t2 + 1) * 16384 + bb * 1024 + sx);
          out_crf[bb * 128 + t2] = (float)sx;
        }
      }
    }
  }
}

// ---------------- scalars & metrics ----
__device__ __forceinline__ float blk_sum(float v, float* rb, int tid) {
  rb[tid] = v; __syncthreads();
  for (int w = 128; w > 0; w >>= 1) { if (tid < w) rb[tid] += rb[tid + w]; __syncthreads(); }
  float r = rb[0]; __syncthreads();
  return r;
}

__global__ __launch_bounds__(256) void finalize_kernel(
    const float* __restrict__ emission, const float* __restrict__ transition,
    const float* __restrict__ u_last, const float* __restrict__ ua_last,
    const float* __restrict__ row_max, const float* __restrict__ row_lse,
    const int* __restrict__ sm_pred, const int* __restrict__ y,
    const int* __restrict__ y_lens, float* __restrict__ d_out) {
  __shared__ float rb[256];
  __shared__ float sZ[16], sZa[16], sLogy[16];
  const int tid = threadIdx.x;
  const float* out_crf = d_out + 1;
  for (int b = 0; b < 16; ++b) {
    const int tb = y_lens[b] - 1;
    float p = 0.f;
    for (int i = tid; i < 1024; i += 256) p += u_last[(size_t)b * 1024 + i];
    p = blk_sum(p, rb, tid);
    if (tid == 0) sZ[b] = logf(p) + (float)tb * 6.931471805599453f;  // ln(1024)
    float q = 0.f;
    for (int i = tid; i < 102; i += 256) q += ua_last[(size_t)b * 102 + i];
    q = blk_sum(q, rb, tid);
    if (tid == 0) sZa[b] = logf(q) + (float)tb * 4.624972813284271f;  // ln(102)
  }
  if (tid < 16) sLogy[tid] = 0.f;
  __syncthreads();
  float a_local = 0, a_maxp = 0, c_sup = 0, c_pred = 0, c_ov = 0, c_match = 0;
  float s_predc = 0, s_ov = 0, s_match = 0;
  for (int r = tid; r < 2048; r += 256) {
    const int b = r >> 7, t = r & 127;
    const int L = y_lens[b];
    if (t < L) {
      const int yv = y[r];
      const float em_y = emission[(size_t)r * 1024 + yv];
      const float lse = row_lse[r];
      a_local += em_y - lse;
      a_maxp += expf(row_max[r] - lse);
      float term = em_y;
      if (t < L - 1) term += transition[(size_t)yv * 1024 + y[r + 1]];
      atomicAdd(&sLogy[b], term);
      const float ypos = (yv > 0) ? 1.f : 0.f;
      c_sup += ypos;
      const int cs = (int)out_crf[r];
      c_pred += (cs > 0) ? 1.f : 0.f;
      c_ov += ((cs > 0) && (yv > 0)) ? 1.f : 0.f;
      c_match += (cs == yv) ? 1.f : 0.f;
      const int ss = sm_pred[r];
      s_predc += (ss > 0) ? 1.f : 0.f;
      s_ov += ((ss > 0) && (yv > 0)) ? 1.f : 0.f;
      s_match += (ss == yv) ? 1.f : 0.f;
    }
  }
  __syncthreads();
  a_local = blk_sum(a_local, rb, tid);
  a_maxp = blk_sum(a_maxp, rb, tid);
  c_sup = blk_sum(c_sup, rb, tid);
  c_pred = blk_sum(c_pred, rb, tid);
  c_ov = blk_sum(c_ov, rb, tid);
  c_match = blk_sum(c_match, rb, tid);
  s_predc = blk_sum(s_predc, rb, tid);
  s_ov = blk_sum(s_ov, rb, tid);
  s_match = blk_sum(s_match, rb, tid);
  if (tid == 0) {
    float tl = 0.f;
    for (int b = 0; b < 16; ++b) tl += (float)y_lens[b];
    float mZ = 0, mZa = 0, dE = 0, dA = 0;
    for (int b = 0; b < 16; ++b) {
      mZ += sZ[b]; mZa += sZa[b];
      dE += sLogy[b] - sZ[b];
      dA += sLogy[b] - sZa[b];
    }
    mZ *= (1.f / 16.f); mZa *= (1.f / 16.f);
    const float sle = -dE * (1.f / 16.f);
    const float sla = -dA * (1.f / 16.f);
    const float slocal = a_local / tl;
    const float maxp = a_maxp / tl;
    const float loss = sla + 0.1f * slocal;
    const float crf_acc = c_match / tl;
    const float crf_prec = (c_pred > 0.f) ? (c_ov / fmaxf(c_pred, 1.f)) : 0.f;
    const float crf_recl = c_ov / fmaxf(c_sup, 1.f);
    const float crf_f1 = (crf_prec > 0.f)
        ? (2.f * crf_prec * crf_recl / fmaxf(crf_prec + crf_recl, 1e-12f)) : 0.f;
    const float sm_acc = s_match / tl;
    const float sm_prec = (s_predc > 0.f) ? (s_ov / fmaxf(s_predc, 1.f)) : 0.f;
    const float sm_recl = s_ov / fmaxf(c_sup, 1.f);
    const float sm_f1 = (sm_prec > 0.f)
        ? (2.f * sm_prec * sm_recl / fmaxf(sm_prec + sm_recl, 1e-12f)) : 0.f;
    d_out[0] = loss;
    d_out[2049] = mZ;
    d_out[2050] = mZa;
    d_out[2051] = sle;
    d_out[2052] = slocal;
    d_out[2053] = maxp;
    d_out[2054] = crf_acc;
    d_out[2055] = crf_f1;
    d_out[2056] = sm_acc;
    d_out[2057] = sm_f1;
  }
}

extern "C" void kernel_launch(void* const* d_in, const int* in_sizes, int n_in,
                              void* d_out, int out_size, void* d_ws, size_t ws_size,
                              hipStream_t stream) {
  const float* x = (const float*)d_in[0];
  const float* stm = (const float*)d_in[1];
  const int* y = (const int*)d_in[2];
  const int* yl = (const int*)d_in[3];
  float* out = (float*)d_out;
  float* ws = (float*)d_ws;

  float* emission = ws + OFF_EM;
  float* transition = ws + OFF_TR;
  unsigned short* expTb = (unsigned short*)(ws + OFF_EXPTB);
  float* u_pp = ws + OFF_UPP;
  float* av_pp = ws + OFF_APP;
  float* u_last = ws + OFF_ULST;
  float* av_last = ws + OFF_ALST;
  float* ua_last = ws + OFF_UALST;
  float* em_top = ws + OFF_ETOP;
  int* top_idx = (int*)(ws + OFF_ITOP);
  float* row_max = ws + OFF_RMAX;
  float* row_lse = ws + OFF_RLSE;
  int* sm_pred = (int*)(ws + OFF_SMP);
  int* bp = (int*)(ws + OFF_BP);
  unsigned* flags = (unsigned*)(ws + OFF_FLG);

  (void)hipMemsetAsync(flags, 0, (size_t)8 * 128 * 64 * FLAG_PAD * sizeof(unsigned), stream);
  gemm_kernel<<<dim3(48, 16), 256, 0, stream>>>(x, stm, emission, transition, expTb);
  topk_kernel<<<2048, 256, 0, stream>>>(emission, em_top, top_idx, row_max, row_lse, sm_pred);
  scan_kernel<<<512, 256, 0, stream>>>(emission, transition, expTb, em_top, top_idx,
                                       yl, u_pp, av_pp, u_last, av_last, ua_last,
                                       bp, flags, out + 1);
  finalize_kernel<<<1, 256, 0, stream>>>(emission, transition, u_last, ua_last,
                                         row_max, row_lse, sm_pred, y, yl, out);
}

// Round 12
// 1914.924 us; speedup vs baseline: 2.3682x; 2.3682x over previous
//
#include <hip/hip_runtime.h>
#include <cstdint>
#include <cstddef>

typedef unsigned long long ull;
typedef unsigned int uint32;

// B=16, T=128, K=1024, D=768, KP=102
// R9 structure (fwd 128 blocks b*8+s 128-col bf16 slices; vit 128 blocks fp32;
// approx 16 block-local) with SELF-ANNOUNCING state: no flags. State lives in
// a 4-deep ring of poisoned buffers; consumers poll the data words directly
// (8B atomic bypass stores can't tear). Producers re-poison their region of
// buf[(t+2)&3] each step (provably consumed), ordered before data by vmcnt.

#define POISON64 0xFFFFFFFFFFFFFFFFull
#define POISON32 0xFFFFFFFFu

// ---- workspace layout (float offsets) ----
#define OFF_EM    ((size_t)0)         // emission   2048*1024 f32
#define OFF_TR    ((size_t)2097152)   // transition 1024*1024 f32
#define OFF_EXPTB ((size_t)3145728)   // expTb      1024*1024 bf16 (ushort)
#define OFF_UPP   ((size_t)3670016)   // u ring     4*16*1024
#define OFF_APP   ((size_t)3735552)   // av ring    4*16*1024
#define OFF_ULST  ((size_t)3801088)   // u at t=tb  16*1024
#define OFF_ALST  ((size_t)3817472)   // av at t=tb 16*1024
#define OFF_UALST ((size_t)3833856)   // ua at t=tb 16*102 (pad 2048)
#define OFF_ETOP  ((size_t)3835904)   // em_top     2048*102
#define OFF_ITOP  ((size_t)4044800)   // top_idx    2048*102 (int)
#define OFF_RMAX  ((size_t)4253696)   // row_max    2048
#define OFF_RLSE  ((size_t)4255744)   // row_lse    2048
#define OFF_SMP   ((size_t)4257792)   // sm_pred    2048 (int)
#define OFF_BP    ((size_t)4259840)   // bp         128*16*1024 (int)
#define OFF_DONE  ((size_t)6356992)   // done lines 16*8*16 uints (poisoned)

__device__ __forceinline__ unsigned short f2bf(float f) {
  uint32 u = __builtin_bit_cast(uint32, f);
  u = (u + 0x7fffu + ((u >> 16) & 1u)) >> 16;
  return (unsigned short)u;
}
__device__ __forceinline__ float bflo(uint32 w) {
  return __builtin_bit_cast(float, w << 16);
}
__device__ __forceinline__ float bfhi(uint32 w) {
  return __builtin_bit_cast(float, w & 0xffff0000u);
}

// ---------------- GEMM: [x_emb; state] (3072x768) @ state^T -> 3072x1024 ----
__global__ __launch_bounds__(256) void gemm_kernel(
    const float* __restrict__ x, const float* __restrict__ stm,
    float* __restrict__ emission, float* __restrict__ transition,
    unsigned short* __restrict__ expTb) {
  __shared__ float As[16][68];
  __shared__ float Bs[16][68];
  const int tid = threadIdx.x;
  const int tx = tid & 15, ty = tid >> 4;
  const int m0 = blockIdx.x * 64, n0 = blockIdx.y * 64;
  const int lr = tid >> 2;
  const int lc = (tid & 3) << 2;
  float acc[4][4] = {};
  const float* aptr;
  {
    int gr = m0 + lr;
    aptr = (gr < 2048) ? (x + (size_t)gr * 768) : (stm + (size_t)(gr - 2048) * 768);
  }
  const float* bptr = stm + (size_t)(n0 + lr) * 768;
  for (int k0 = 0; k0 < 768; k0 += 16) {
    float4 a4 = *(const float4*)(aptr + k0 + lc);
    float4 b4 = *(const float4*)(bptr + k0 + lc);
    __syncthreads();
    As[lc + 0][lr] = a4.x; As[lc + 1][lr] = a4.y; As[lc + 2][lr] = a4.z; As[lc + 3][lr] = a4.w;
    Bs[lc + 0][lr] = b4.x; Bs[lc + 1][lr] = b4.y; Bs[lc + 2][lr] = b4.z; Bs[lc + 3][lr] = b4.w;
    __syncthreads();
#pragma unroll
    for (int kk = 0; kk < 16; ++kk) {
      float a[4], b[4];
#pragma unroll
      for (int q = 0; q < 4; ++q) a[q] = As[kk][ty * 4 + q];
#pragma unroll
      for (int q = 0; q < 4; ++q) b[q] = Bs[kk][tx * 4 + q];
#pragma unroll
      for (int i2 = 0; i2 < 4; ++i2)
#pragma unroll
        for (int j2 = 0; j2 < 4; ++j2) acc[i2][j2] += a[i2] * b[j2];
    }
  }
  const float rs = 0.03608439182435161f;  // 1/sqrt(768)
#pragma unroll
  for (int i2 = 0; i2 < 4; ++i2) {
    int r = m0 + ty * 4 + i2;
#pragma unroll
    for (int j2 = 0; j2 < 4; ++j2) {
      int c = n0 + tx * 4 + j2;
      float v = acc[i2][j2] * rs;
      if (r < 2048) {
        emission[(size_t)r * 1024 + c] = v;
      } else {
        size_t o = (size_t)(r - 2048) * 1024 + c;
        transition[o] = v;
        expTb[o] = f2bf(expf(v));
      }
    }
  }
}

// ---------------- per-row bitonic sort -> top-102 set, max, lse, argmax ----
__global__ __launch_bounds__(256) void topk_kernel(
    const float* __restrict__ emission, float* __restrict__ em_top,
    int* __restrict__ top_idx, float* __restrict__ row_max,
    float* __restrict__ row_lse, int* __restrict__ sm_pred) {
  __shared__ float v[1024];
  __shared__ int ix[1024];
  __shared__ float rb[256];
  const int row = blockIdx.x;
  const int tid = threadIdx.x;
  const float* e = emission + (size_t)row * 1024;
  for (int p = tid; p < 1024; p += 256) { v[p] = e[p]; ix[p] = p; }
  __syncthreads();
  for (int k = 2; k <= 1024; k <<= 1) {
    for (int j = k >> 1; j > 0; j >>= 1) {
      for (int p = tid; p < 1024; p += 256) {
        int l = p ^ j;
        if (l > p) {
          float va = v[p], vb = v[l];
          int ia = ix[p], ib = ix[l];
          bool aBefore = (va > vb) || (va == vb && ia < ib);
          bool up = ((p & k) == 0);
          if (up ? !aBefore : aBefore) { v[p] = vb; v[l] = va; ix[p] = ib; ix[l] = ia; }
        }
      }
      __syncthreads();
    }
  }
  float mx = v[0];
  float s = 0.f;
  for (int p = tid; p < 1024; p += 256) s += expf(v[p] - mx);
  rb[tid] = s; __syncthreads();
  for (int w = 128; w > 0; w >>= 1) { if (tid < w) rb[tid] += rb[tid + w]; __syncthreads(); }
  if (tid == 0) {
    row_max[row] = mx;
    row_lse[row] = mx + logf(rb[0]);
    sm_pred[row] = ix[0];
  }
  for (int p = tid; p < 102; p += 256) {
    em_top[(size_t)row * 102 + p] = v[p];
    top_idx[(size_t)row * 102 + p] = ix[p];
  }
}

// ---------------- coherence helpers ----
__device__ __forceinline__ void store_bypass2(float* p, float2 v) {
  __hip_atomic_store((ull*)p, __builtin_bit_cast(ull, v),
                     __ATOMIC_RELAXED, __HIP_MEMORY_SCOPE_AGENT);
}
__device__ __forceinline__ void store_bypass_i2(int* p, int2 v) {
  __hip_atomic_store((ull*)p, __builtin_bit_cast(ull, v),
                     __ATOMIC_RELAXED, __HIP_MEMORY_SCOPE_AGENT);
}
__device__ __forceinline__ float load_bypass_f(const float* p) {
  return __hip_atomic_load(p, __ATOMIC_RELAXED, __HIP_MEMORY_SCOPE_AGENT);
}
__device__ __forceinline__ int load_bypass_i(const int* p) {
  return __hip_atomic_load(p, __ATOMIC_RELAXED, __HIP_MEMORY_SCOPE_AGENT);
}
__device__ __forceinline__ void store_bypass_u64(ull* p, ull v) {
  __hip_atomic_store(p, v, __ATOMIC_RELAXED, __HIP_MEMORY_SCOPE_AGENT);
}
__device__ __forceinline__ ull load_bypass_u64(const ull* p) {
  return __hip_atomic_load(p, __ATOMIC_RELAXED, __HIP_MEMORY_SCOPE_AGENT);
}
__device__ __forceinline__ void store_bypass_u32(uint32* p, uint32 v) {
  __hip_atomic_store(p, v, __ATOMIC_RELAXED, __HIP_MEMORY_SCOPE_AGENT);
}
__device__ __forceinline__ uint32 load_bypass_u32(const uint32* p) {
  return __hip_atomic_load(p, __ATOMIC_RELAXED, __HIP_MEMORY_SCOPE_AGENT);
}

// Self-synchronizing stage: poll the data words until non-poison (8B atomic
// stores can't tear; real values are never the poison NaN pattern).
__device__ __forceinline__ void stage_poll(const float* __restrict__ src,
                                           float* __restrict__ lds, int tid) {
  const ull* s8 = (const ull*)src;
  ull* l8 = (ull*)lds;
  ull a = load_bypass_u64(s8 + tid);
  ull b = load_bypass_u64(s8 + tid + 256);
  while (a == POISON64) { __builtin_amdgcn_s_sleep(1); a = load_bypass_u64(s8 + tid); }
  while (b == POISON64) { __builtin_amdgcn_s_sleep(1); b = load_bypass_u64(s8 + tid + 256); }
  l8[tid] = a;
  l8[tid + 256] = b;
}

// ---------------- poison the rings + done lines (runs each launch) ----------
__global__ __launch_bounds__(256) void poison_kernel(
    ull* __restrict__ uring, ull* __restrict__ aring, ull* __restrict__ done) {
  const int idx = blockIdx.x * 256 + threadIdx.x;   // 32768 threads
  store_bypass_u64(uring + idx, POISON64);
  store_bypass_u64(aring + idx, POISON64);
  if (idx < 1024) store_bypass_u64(done + idx, POISON64);
}

// ---------------- persistent scan ----------------
__global__ __launch_bounds__(256, 1) void scan_kernel(
    const float* __restrict__ em, const float* __restrict__ tr,
    const unsigned short* __restrict__ expTb, const float* __restrict__ em_top,
    const int* __restrict__ top_idx, const int* __restrict__ y_lens,
    float* __restrict__ u_ring, float* __restrict__ av_ring,
    float* __restrict__ u_last, float* __restrict__ av_last,
    float* __restrict__ ua_last, int* __restrict__ bp,
    uint32* __restrict__ done, float* __restrict__ out_crf) {
  __shared__ float st[1024];     // staged state for my batch
  __shared__ float psv[896];
  __shared__ int psi[384];
  __shared__ float sua[2][102];
  __shared__ int sidxp[102], sidxc[102];
  __shared__ float aps[102];
  __shared__ float swv[4];
  __shared__ int swi[4];
  const int bid = blockIdx.x, tid = threadIdx.x;

  if (bid < 128) {
    // ======== forward: batch b, slice s (128 cols, bf16 expT) ========
    const int b = bid >> 3, s = bid & 7;
    const int tb = y_lens[b] - 1;
    const int tl = tid & 31, h = tid >> 5;   // 4 cols/lane, i-eighth h
    const int j = s * 128 + tl * 4;
    if (h == 0) {
      const float4 e4 = *(const float4*)(em + (size_t)(b * 128) * 1024 + j);
      float4 v;
      v.x = expf(e4.x); v.y = expf(e4.y); v.z = expf(e4.z); v.w = expf(e4.w);
      float* dst = u_ring + b * 1024 + j;          // buf 0
      store_bypass2(dst, make_float2(v.x, v.y));
      store_bypass2(dst + 2, make_float2(v.z, v.w));
      if (tb == 0) *(float4*)(u_last + b * 1024 + j) = v;
    }
    for (int t = 1; t < 128; ++t) {
      // re-poison my region of the buffer to be written at t+2 (provably
      // consumed), ordered before this step's data stores by the vmcnt.
      if (tid < 64) {
        if (h == 0) {
          ull* pz = (ull*)(u_ring + (size_t)((t + 2) & 3) * 16384 + b * 1024 + j);
          store_bypass_u64(pz, POISON64);
          store_bypass_u64(pz + 1, POISON64);
        }
        asm volatile("s_waitcnt vmcnt(0)" ::: "memory");
      }
      stage_poll(u_ring + (size_t)((t - 1) & 3) * 16384 + b * 1024, st, tid);
      __syncthreads();
      float a0 = 0.f, a1 = 0.f, a2 = 0.f, a3 = 0.f;
#pragma unroll 4
      for (int i = h * 128; i < h * 128 + 128; ++i) {
        const uint2 w = *(const uint2*)(expTb + (size_t)i * 1024 + j);
        const float ui = st[i];
        a0 += ui * bflo(w.x); a1 += ui * bfhi(w.x);
        a2 += ui * bflo(w.y); a3 += ui * bfhi(w.y);
      }
      if (h) {
        float* p = psv + (h - 1) * 128 + tl * 4;
        p[0] = a0; p[1] = a1; p[2] = a2; p[3] = a3;
      }
      __syncthreads();
      if (h == 0) {
#pragma unroll
        for (int q = 0; q < 7; ++q) {
          const float* p = psv + q * 128 + tl * 4;
          a0 += p[0]; a1 += p[1]; a2 += p[2]; a3 += p[3];
        }
        const float4 e4 = *(const float4*)(em + ((size_t)b * 128 + t) * 1024 + j);
        float4 v;
        v.x = a0 * expf(e4.x) * (1.0f / 1024.0f);
        v.y = a1 * expf(e4.y) * (1.0f / 1024.0f);
        v.z = a2 * expf(e4.z) * (1.0f / 1024.0f);
        v.w = a3 * expf(e4.w) * (1.0f / 1024.0f);
        float* dst = u_ring + (size_t)(t & 3) * 16384 + b * 1024 + j;
        store_bypass2(dst, make_float2(v.x, v.y));
        store_bypass2(dst + 2, make_float2(v.z, v.w));
        if (t == tb) *(float4*)(u_last + b * 1024 + j) = v;
      }
    }
  } else if (bid < 256) {
    // ======== viterbi: batch b, slice s (128 cols, fp32 tr) ========
    const int local = bid - 128;
    const int b = local >> 3, s = local & 7;
    const int tb = y_lens[b] - 1;
    const int tl = tid & 63, h = tid >> 6;   // 2 cols/lane, i-quarter h
    const int j = s * 128 + tl * 2;
    if (h == 0) {
      const float2 e2 = *(const float2*)(em + (size_t)(b * 128) * 1024 + j);
      store_bypass2(av_ring + b * 1024 + j, e2);   // buf 0
      if (tb == 0) store_bypass2(av_last + b * 1024 + j, e2);
    }
    for (int t = 1; t < 128; ++t) {
      if (tid < 64) {   // wave 0 == h 0 lanes
        ull* pz = (ull*)(av_ring + (size_t)((t + 2) & 3) * 16384 + b * 1024 + j);
        store_bypass_u64(pz, POISON64);
        asm volatile("s_waitcnt vmcnt(0)" ::: "memory");
      }
      stage_poll(av_ring + (size_t)((t - 1) & 3) * 16384 + b * 1024, st, tid);
      __syncthreads();
      float m0 = -3.0e38f, m1 = -3.0e38f;
      int x0 = 0x7fffffff, x1 = 0x7fffffff;
#pragma unroll 4
      for (int i = h * 256; i < h * 256 + 256; ++i) {
        const float2 t2 = *(const float2*)(tr + (size_t)i * 1024 + j);
        const float ai = st[i];
        float c0 = ai + t2.x;
        float c1 = ai + t2.y;
        if (c0 > m0) { m0 = c0; x0 = i; }
        if (c1 > m1) { m1 = c1; x1 = i; }
      }
      if (h) {
        psv[(h - 1) * 128 + tl * 2] = m0; psv[(h - 1) * 128 + tl * 2 + 1] = m1;
        psi[(h - 1) * 128 + tl * 2] = x0; psi[(h - 1) * 128 + tl * 2 + 1] = x1;
      }
      __syncthreads();
      if (h == 0) {
#pragma unroll
        for (int q = 0; q < 3; ++q) {
          float p0 = psv[q * 128 + tl * 2], p1 = psv[q * 128 + tl * 2 + 1];
          int y0 = psi[q * 128 + tl * 2], y1 = psi[q * 128 + tl * 2 + 1];
          if (p0 > m0) { m0 = p0; x0 = y0; }  // ties keep lower h = lower i
          if (p1 > m1) { m1 = p1; x1 = y1; }
        }
        const float2 e2 = *(const float2*)(em + ((size_t)b * 128 + t) * 1024 + j);
        float2 nv = make_float2(m0 + e2.x, m1 + e2.y);
        store_bypass2(av_ring + (size_t)(t & 3) * 16384 + b * 1024 + j, nv);
        store_bypass_i2(bp + (size_t)t * 16384 + b * 1024 + j, make_int2(x0, x1));
        if (t == tb) store_bypass2(av_last + b * 1024 + j, nv);
      }
    }
    // announce completion (drains all wave-0 stores first)
    if (tid == 0) {
      asm volatile("s_waitcnt vmcnt(0)" ::: "memory");
      store_bypass_u32(done + (size_t)(b * 8 + s) * 16, 0u);
    }
    // ---- backtrace: slice-0 block; wait for all slices' done lines ----
    if (s == 0) {
      if (tid < 8) {
        const uint32* dp = done + (size_t)(b * 8 + tid) * 16;
        while (load_bypass_u32(dp) == POISON32) __builtin_amdgcn_s_sleep(1);
      }
      __syncthreads();
      const int tbb = tb;
      for (int t2 = tbb + 1 + tid; t2 < 128; t2 += 256) out_crf[b * 128 + t2] = 0.f;
      const float* al = av_last + b * 1024;
      float bv = -3.0e38f;
      int bi = 0x7fffffff;
      for (int i = tid; i < 1024; i += 256) {
        float val = load_bypass_f(al + i);
        if (val > bv || (val == bv && i < bi)) { bv = val; bi = i; }
      }
      for (int off = 32; off > 0; off >>= 1) {
        float ov = __shfl_xor(bv, off);
        int oi = __shfl_xor(bi, off);
        if (ov > bv || (ov == bv && oi < bi)) { bv = ov; bi = oi; }
      }
      if ((tid & 63) == 0) { swv[tid >> 6] = bv; swi[tid >> 6] = bi; }
      __syncthreads();
      if (tid == 0) {
        for (int q = 1; q < 4; ++q)
          if (swv[q] > bv || (swv[q] == bv && swi[q] < bi)) { bv = swv[q]; bi = swi[q]; }
        int sx = bi;
        out_crf[b * 128 + tbb] = (float)sx;
        for (int t2 = tbb - 1; t2 >= 0; --t2) {
          sx = load_bypass_i(bp + (size_t)(t2 + 1) * 16384 + b * 1024 + sx);
          out_crf[b * 128 + t2] = (float)sx;
        }
      }
    }
  } else {
    // ======== approx: one block per batch, fully block-local ========
    const int b = bid - 256;
    const int tb = y_lens[b] - 1;
    const int j2 = tid & 127, h2 = tid >> 7;
    if (tid < 102) {
      float v = expf(em_top[(size_t)(b * 128) * 102 + tid]);
      sua[0][tid] = v;
      if (tb == 0) ua_last[b * 102 + tid] = v;
    }
    __syncthreads();
    for (int t = 1; t < 128; ++t) {
      if (tid < 102) {
        sidxp[tid] = top_idx[((size_t)b * 128 + (t - 1)) * 102 + tid];
        sidxc[tid] = top_idx[((size_t)b * 128 + t) * 102 + tid];
      }
      __syncthreads();
      float acc2 = 0.f;
      if (j2 < 102) {
        const int col = sidxc[j2];
        const float* up = sua[(t - 1) & 1];
        for (int i = h2 * 51; i < h2 * 51 + 51; ++i)
          acc2 += up[i] * bflo((uint32)expTb[(size_t)sidxp[i] * 1024 + col]);
      }
      if (h2 == 1 && j2 < 102) aps[j2] = acc2;
      __syncthreads();
      if (h2 == 0 && j2 < 102) {
        acc2 += aps[j2];
        float e = em_top[((size_t)b * 128 + t) * 102 + j2];
        float nv = acc2 * expf(e) * (1.0f / 102.0f);
        sua[t & 1][j2] = nv;
        if (t == tb) ua_last[b * 102 + j2] = nv;
      }
      __syncthreads();
    }
  }
}

// ---------------- scalars & metrics ----
__device__ __forceinline__ float blk_sum(float v, float* rb, int tid) {
  rb[tid] = v; __syncthreads();
  for (int w = 128; w > 0; w >>= 1) { if (tid < w) rb[tid] += rb[tid + w]; __syncthreads(); }
  float r = rb[0]; __syncthreads();
  return r;
}

__global__ __launch_bounds__(256) void finalize_kernel(
    const float* __restrict__ emission, const float* __restrict__ transition,
    const float* __restrict__ u_last, const float* __restrict__ ua_last,
    const float* __restrict__ row_max, const float* __restrict__ row_lse,
    const int* __restrict__ sm_pred, const int* __restrict__ y,
    const int* __restrict__ y_lens, float* __restrict__ d_out) {
  __shared__ float rb[256];
  __shared__ float sZ[16], sZa[16], sLogy[16];
  const int tid = threadIdx.x;
  const float* out_crf = d_out + 1;
  for (int b = 0; b < 16; ++b) {
    const int tb = y_lens[b] - 1;
    float p = 0.f;
    for (int i = tid; i < 1024; i += 256) p += u_last[(size_t)b * 1024 + i];
    p = blk_sum(p, rb, tid);
    if (tid == 0) sZ[b] = logf(p) + (float)tb * 6.931471805599453f;  // ln(1024)
    float q = 0.f;
    for (int i = tid; i < 102; i += 256) q += ua_last[(size_t)b * 102 + i];
    q = blk_sum(q, rb, tid);
    if (tid == 0) sZa[b] = logf(q) + (float)tb * 4.624972813284271f;  // ln(102)
  }
  if (tid < 16) sLogy[tid] = 0.f;
  __syncthreads();
  float a_local = 0, a_maxp = 0, c_sup = 0, c_pred = 0, c_ov = 0, c_match = 0;
  float s_predc = 0, s_ov = 0, s_match = 0;
  for (int r = tid; r < 2048; r += 256) {
    const int b = r >> 7, t = r & 127;
    const int L = y_lens[b];
    if (t < L) {
      const int yv = y[r];
      const float em_y = emission[(size_t)r * 1024 + yv];
      const float lse = row_lse[r];
      a_local += em_y - lse;
      a_maxp += expf(row_max[r] - lse);
      float term = em_y;
      if (t < L - 1) term += transition[(size_t)yv * 1024 + y[r + 1]];
      atomicAdd(&sLogy[b], term);
      const float ypos = (yv > 0) ? 1.f : 0.f;
      c_sup += ypos;
      const int cs = (int)out_crf[r];
      c_pred += (cs > 0) ? 1.f : 0.f;
      c_ov += ((cs > 0) && (yv > 0)) ? 1.f : 0.f;
      c_match += (cs == yv) ? 1.f : 0.f;
      const int ss = sm_pred[r];
      s_predc += (ss > 0) ? 1.f : 0.f;
      s_ov += ((ss > 0) && (yv > 0)) ? 1.f : 0.f;
      s_match += (ss == yv) ? 1.f : 0.f;
    }
  }
  __syncthreads();
  a_local = blk_sum(a_local, rb, tid);
  a_maxp = blk_sum(a_maxp, rb, tid);
  c_sup = blk_sum(c_sup, rb, tid);
  c_pred = blk_sum(c_pred, rb, tid);
  c_ov = blk_sum(c_ov, rb, tid);
  c_match = blk_sum(c_match, rb, tid);
  s_predc = blk_sum(s_predc, rb, tid);
  s_ov = blk_sum(s_ov, rb, tid);
  s_match = blk_sum(s_match, rb, tid);
  if (tid == 0) {
    float tl = 0.f;
    for (int b = 0; b < 16; ++b) tl += (float)y_lens[b];
    float mZ = 0, mZa = 0, dE = 0, dA = 0;
    for (int b = 0; b < 16; ++b) {
      mZ += sZ[b]; mZa += sZa[b];
      dE += sLogy[b] - sZ[b];
      dA += sLogy[b] - sZa[b];
    }
    mZ *= (1.f / 16.f); mZa *= (1.f / 16.f);
    const float sle = -dE * (1.f / 16.f);
    const float sla = -dA * (1.f / 16.f);
    const float slocal = a_local / tl;
    const float maxp = a_maxp / tl;
    const float loss = sla + 0.1f * slocal;
    const float crf_acc = c_match / tl;
    const float crf_prec = (c_pred > 0.f) ? (c_ov / fmaxf(c_pred, 1.f)) : 0.f;
    const float crf_recl = c_ov / fmaxf(c_sup, 1.f);
    const float crf_f1 = (crf_prec > 0.f)
        ? (2.f * crf_prec * crf_recl / fmaxf(crf_prec + crf_recl, 1e-12f)) : 0.f;
    const float sm_acc = s_match / tl;
    const float sm_prec = (s_predc > 0.f) ? (s_ov / fmaxf(s_predc, 1.f)) : 0.f;
    const float sm_recl = s_ov / fmaxf(c_sup, 1.f);
    const float sm_f1 = (sm_prec > 0.f)
        ? (2.f * sm_prec * sm_recl / fmaxf(sm_prec + sm_recl, 1e-12f)) : 0.f;
    d_out[0] = loss;
    d_out[2049] = mZ;
    d_out[2050] = mZa;
    d_out[2051] = sle;
    d_out[2052] = slocal;
    d_out[2053] = maxp;
    d_out[2054] = crf_acc;
    d_out[2055] = crf_f1;
    d_out[2056] = sm_acc;
    d_out[2057] = sm_f1;
  }
}

extern "C" void kernel_launch(void* const* d_in, const int* in_sizes, int n_in,
                              void* d_out, int out_size, void* d_ws, size_t ws_size,
                              hipStream_t stream) {
  const float* x = (const float*)d_in[0];
  const float* stm = (const float*)d_in[1];
  const int* y = (const int*)d_in[2];
  const int* yl = (const int*)d_in[3];
  float* out = (float*)d_out;
  float* ws = (float*)d_ws;

  float* emission = ws + OFF_EM;
  float* transition = ws + OFF_TR;
  unsigned short* expTb = (unsigned short*)(ws + OFF_EXPTB);
  float* u_ring = ws + OFF_UPP;
  float* av_ring = ws + OFF_APP;
  float* u_last = ws + OFF_ULST;
  float* av_last = ws + OFF_ALST;
  float* ua_last = ws + OFF_UALST;
  float* em_top = ws + OFF_ETOP;
  int* top_idx = (int*)(ws + OFF_ITOP);
  float* row_max = ws + OFF_RMAX;
  float* row_lse = ws + OFF_RLSE;
  int* sm_pred = (int*)(ws + OFF_SMP);
  int* bp = (int*)(ws + OFF_BP);
  uint32* done = (uint32*)(ws + OFF_DONE);

  poison_kernel<<<128, 256, 0, stream>>>((ull*)u_ring, (ull*)av_ring, (ull*)done);
  gemm_kernel<<<dim3(48, 16), 256, 0, stream>>>(x, stm, emission, transition, expTb);
  topk_kernel<<<2048, 256, 0, stream>>>(emission, em_top, top_idx, row_max, row_lse, sm_pred);
  scan_kernel<<<272, 256, 0, stream>>>(emission, transition, expTb, em_top, top_idx,
                                       yl, u_ring, av_ring, u_last, av_last, ua_last,
                                       bp, done, out + 1);
  finalize_kernel<<<1, 256, 0, stream>>>(emission, transition, u_last, ua_last,
                                         row_max, row_lse, sm_pred, y, yl, out);
}